// Round 1
// baseline (946.957 us; speedup 1.0000x reference)
//
#include <hip/hip_runtime.h>

// ConformalGCN: 2-layer GCN, N=100000 nodes, E=1600000 edges (+ self loops),
// IN=128 -> HID=64 (relu) -> OUT=96. fp32 throughout.
//
// Pipeline:
//   deg[n]  = #incoming edges + 1 (self loop);  dinv = rsqrt(deg)
//   h   = x @ W1                      (GEMM1, 100000x128 @ 128x64)
//   a1  = A_norm @ h                  (self-init + atomic edge scatter)
//   h1r = relu(a1 + b1)
//   a2  = A_norm @ h1r                (self-init + atomic edge scatter)
//   out = a2 @ W2 + b2                (GEMM2, 100000x64 @ 64x96)

#define IN_F  128
#define HID_F 64
#define OUT_F 96

__global__ __launch_bounds__(256) void zero_deg(int* __restrict__ deg, int n) {
    for (int i = blockIdx.x * 256 + threadIdx.x; i < n; i += gridDim.x * 256)
        deg[i] = 0;
}

__global__ __launch_bounds__(256) void count_deg(const int* __restrict__ dst,
                                                 int* __restrict__ deg, int E) {
    for (int e = blockIdx.x * 256 + threadIdx.x; e < E; e += gridDim.x * 256)
        atomicAdd(&deg[dst[e]], 1);
}

__global__ __launch_bounds__(256) void calc_dinv(const int* __restrict__ deg,
                                                 float* __restrict__ dinv, int n) {
    for (int i = blockIdx.x * 256 + threadIdx.x; i < n; i += gridDim.x * 256)
        dinv[i] = rsqrtf((float)(deg[i] + 1));   // +1 self loop; always > 0
}

// h[n][64] = x[n][128] @ W1[128][64].  One wave per row; lane j owns col j.
__global__ __launch_bounds__(256) void gemm1(const float* __restrict__ x,
                                             const float* __restrict__ W1,
                                             float* __restrict__ h, int n) {
    __shared__ float w[IN_F * HID_F];   // 32 KiB
    __shared__ float xs[4][IN_F];       // 2 KiB, per-wave row staging
    for (int i = threadIdx.x; i < IN_F * HID_F; i += 256) w[i] = W1[i];
    __syncthreads();
    const int wave = threadIdx.x >> 6, lane = threadIdx.x & 63;
    for (int row = blockIdx.x * 4 + wave; row < n; row += gridDim.x * 4) {
        float2 v = *(const float2*)(x + (size_t)row * IN_F + lane * 2);
        xs[wave][lane * 2]     = v.x;
        xs[wave][lane * 2 + 1] = v.y;
        float acc = 0.f;
#pragma unroll 8
        for (int k = 0; k < IN_F; ++k)
            acc = fmaf(xs[wave][k], w[k * HID_F + lane], acc);
        h[(size_t)row * HID_F + lane] = acc;
    }
}

// agg[n][f] = h[n][f] * dinv[n]^2   (self-loop contribution, also zero-fills)
__global__ __launch_bounds__(256) void self_init(const float* __restrict__ hin,
                                                 const float* __restrict__ dinv,
                                                 float* __restrict__ agg, int n) {
    int total = n * HID_F;
    for (int i = blockIdx.x * 256 + threadIdx.x; i < total; i += gridDim.x * 256) {
        float d = dinv[i >> 6];
        agg[i] = hin[i] * d * d;
    }
}

// agg[dst][f] += h[src][f] * dinv[src]*dinv[dst].  4 edges/block, lane = feature.
__global__ __launch_bounds__(256) void edge_agg(const int* __restrict__ src,
                                                const int* __restrict__ dst,
                                                const float* __restrict__ dinv,
                                                const float* __restrict__ hin,
                                                float* __restrict__ agg, int E) {
    int e = blockIdx.x * 4 + (threadIdx.x >> 6);
    int f = threadIdx.x & 63;
    if (e >= E) return;
    int s = src[e], d = dst[e];
    float wgt = dinv[s] * dinv[d];
    atomicAdd(&agg[(size_t)d * HID_F + f], hin[(size_t)s * HID_F + f] * wgt);
}

__global__ __launch_bounds__(256) void relu_bias(const float* __restrict__ in,
                                                 const float* __restrict__ b1,
                                                 float* __restrict__ outv, int total) {
    for (int i = blockIdx.x * 256 + threadIdx.x; i < total; i += gridDim.x * 256) {
        float v = in[i] + b1[i & (HID_F - 1)];
        outv[i] = v > 0.f ? v : 0.f;
    }
}

// out[n][96] = agg[n][64] @ W2[64][96] + b2
__global__ __launch_bounds__(256) void gemm2(const float* __restrict__ agg,
                                             const float* __restrict__ W2,
                                             const float* __restrict__ b2,
                                             float* __restrict__ out, int n) {
    __shared__ float w[HID_F * OUT_F];  // 24 KiB
    __shared__ float bs[OUT_F];
    for (int i = threadIdx.x; i < HID_F * OUT_F; i += 256) w[i] = W2[i];
    for (int i = threadIdx.x; i < OUT_F; i += 256) bs[i] = b2[i];
    __syncthreads();
    int total = n * OUT_F;
    for (int idx = blockIdx.x * 256 + threadIdx.x; idx < total; idx += gridDim.x * 256) {
        int r = idx / OUT_F, j = idx - r * OUT_F;
        const float* a = agg + (size_t)r * HID_F;
        float acc = bs[j];
#pragma unroll
        for (int k = 0; k < HID_F; ++k)
            acc = fmaf(a[k], w[k * OUT_F + j], acc);
        out[idx] = acc;
    }
}

extern "C" void kernel_launch(void* const* d_in, const int* in_sizes, int n_in,
                              void* d_out, int out_size, void* d_ws, size_t ws_size,
                              hipStream_t stream) {
    const float* x  = (const float*)d_in[0];
    const int*   ei = (const int*)d_in[1];
    const float* W1 = (const float*)d_in[2];
    const float* b1 = (const float*)d_in[3];
    const float* W2 = (const float*)d_in[4];
    const float* b2 = (const float*)d_in[5];
    float* out = (float*)d_out;

    const int n = in_sizes[0] / IN_F;     // 100000
    const int E = in_sizes[1] / 2;        // 1600000
    const int* src = ei;
    const int* dst = ei + E;

    char* ws = (char*)d_ws;
    int*   deg  = (int*)ws;                                   // n ints
    float* dinv = (float*)(ws + (size_t)n * 4);               // n floats
    float* bufA = (float*)(ws + (size_t)n * 8);               // n*64 floats
    float* bufB = bufA + (size_t)n * HID_F;                   // n*64 floats

    zero_deg <<<512, 256, 0, stream>>>(deg, n);
    count_deg<<<2048, 256, 0, stream>>>(dst, deg, E);
    calc_dinv<<<512, 256, 0, stream>>>(deg, dinv, n);

    // layer 1
    gemm1    <<<2048, 256, 0, stream>>>(x, W1, bufA, n);
    self_init<<<2048, 256, 0, stream>>>(bufA, dinv, bufB, n);
    edge_agg <<<(E + 3) / 4, 256, 0, stream>>>(src, dst, dinv, bufA, bufB, E);
    relu_bias<<<2048, 256, 0, stream>>>(bufB, b1, bufA, n * HID_F);

    // layer 2 (aggregate 64-wide h1, then project to 96)
    self_init<<<2048, 256, 0, stream>>>(bufA, dinv, bufB, n);
    edge_agg <<<(E + 3) / 4, 256, 0, stream>>>(src, dst, dinv, bufA, bufB, E);
    gemm2    <<<2048, 256, 0, stream>>>(bufB, W2, b2, out, n);
}

// Round 2
// 621.181 us; speedup vs baseline: 1.5244x; 1.5244x over previous
//
#include <hip/hip_runtime.h>

// ConformalGCN: 2-layer GCN, N=100000, E=1600000 (+self loops), fp32.
// R1: CSR-by-destination gather aggregation (replaces atomic scatter).
//
//   deg -> dinv -> prefix-sum -> CSR fill (src, w=dinv[s]*dinv[d])
//   h   = x @ W1                         (gemm1)
//   h1r = relu(A_csr @ h + b1)           (csr_agg<RELU=1>, self-loop fused)
//   a2  = A_csr @ h1r                    (csr_agg<RELU=0>)
//   out = a2 @ W2 + b2                   (gemm2)

#define IN_F  128
#define HID_F 64
#define OUT_F 96

__global__ __launch_bounds__(256) void zero_deg(int* __restrict__ deg, int n) {
    for (int i = blockIdx.x * 256 + threadIdx.x; i < n; i += gridDim.x * 256)
        deg[i] = 0;
}

__global__ __launch_bounds__(256) void count_deg(const int* __restrict__ dst,
                                                 int* __restrict__ deg, int E) {
    for (int e = blockIdx.x * 256 + threadIdx.x; e < E; e += gridDim.x * 256)
        atomicAdd(&deg[dst[e]], 1);
}

__global__ __launch_bounds__(256) void calc_dinv(const int* __restrict__ deg,
                                                 float* __restrict__ dinv, int n) {
    for (int i = blockIdx.x * 256 + threadIdx.x; i < n; i += gridDim.x * 256)
        dinv[i] = rsqrtf((float)(deg[i] + 1));   // +1 self loop; always > 0
}

// ---- hierarchical exclusive prefix sum over deg[n] (1024 elems/block) ----
__global__ __launch_bounds__(256) void scan_blocks(const int* __restrict__ deg,
                                                   int* __restrict__ pre,
                                                   int* __restrict__ bsum, int n) {
    __shared__ int lds[256];
    const int t = threadIdx.x;
    const int base = blockIdx.x * 1024 + t * 4;
    int v0 = (base + 0 < n) ? deg[base + 0] : 0;
    int v1 = (base + 1 < n) ? deg[base + 1] : 0;
    int v2 = (base + 2 < n) ? deg[base + 2] : 0;
    int v3 = (base + 3 < n) ? deg[base + 3] : 0;
    int s = v0 + v1 + v2 + v3;
    lds[t] = s;
    __syncthreads();
    for (int off = 1; off < 256; off <<= 1) {
        int add = (t >= off) ? lds[t - off] : 0;
        __syncthreads();
        lds[t] += add;
        __syncthreads();
    }
    int e = lds[t] - s;   // exclusive prefix of this thread within block
    if (base + 0 < n) pre[base + 0] = e;
    e += v0;
    if (base + 1 < n) pre[base + 1] = e;
    e += v1;
    if (base + 2 < n) pre[base + 2] = e;
    e += v2;
    if (base + 3 < n) pre[base + 3] = e;
    if (t == 255) bsum[blockIdx.x] = lds[255];
}

__global__ __launch_bounds__(256) void scan_bsums(const int* __restrict__ bsum,
                                                  int* __restrict__ boffs, int nb) {
    __shared__ int lds[256];
    const int t = threadIdx.x;
    int v = (t < nb) ? bsum[t] : 0;
    lds[t] = v;
    __syncthreads();
    for (int off = 1; off < 256; off <<= 1) {
        int add = (t >= off) ? lds[t - off] : 0;
        __syncthreads();
        lds[t] += add;
        __syncthreads();
    }
    boffs[t] = lds[t] - v;   // exclusive
}

__global__ __launch_bounds__(256) void add_offsets(const int* __restrict__ pre,
                                                   const int* __restrict__ boffs,
                                                   int* __restrict__ rowptr,
                                                   int* __restrict__ writepos,
                                                   int n, int E) {
    for (int i = blockIdx.x * 256 + threadIdx.x; i < n; i += gridDim.x * 256) {
        int r = pre[i] + boffs[i >> 10];
        rowptr[i] = r;
        writepos[i] = r;
        if (i == 0) rowptr[n] = E;
    }
}

// csr[pos] = (src, dinv[src]*dinv[dst] as bits)
__global__ __launch_bounds__(256) void fill_csr(const int* __restrict__ src,
                                                const int* __restrict__ dst,
                                                const float* __restrict__ dinv,
                                                int* __restrict__ writepos,
                                                int2* __restrict__ csr, int E) {
    for (int e = blockIdx.x * 256 + threadIdx.x; e < E; e += gridDim.x * 256) {
        int s = src[e], d = dst[e];
        int pos = atomicAdd(&writepos[d], 1);
        csr[pos] = make_int2(s, __float_as_int(dinv[s] * dinv[d]));
    }
}

// h[n][64] = x[n][128] @ W1[128][64].  One wave per row; lane j owns col j.
__global__ __launch_bounds__(256) void gemm1(const float* __restrict__ x,
                                             const float* __restrict__ W1,
                                             float* __restrict__ h, int n) {
    __shared__ float w[IN_F * HID_F];   // 32 KiB
    __shared__ float xs[4][IN_F];
    for (int i = threadIdx.x; i < IN_F * HID_F; i += 256) w[i] = W1[i];
    __syncthreads();
    const int wave = threadIdx.x >> 6, lane = threadIdx.x & 63;
    for (int row = blockIdx.x * 4 + wave; row < n; row += gridDim.x * 4) {
        float2 v = *(const float2*)(x + (size_t)row * IN_F + lane * 2);
        xs[wave][lane * 2]     = v.x;
        xs[wave][lane * 2 + 1] = v.y;
        float acc = 0.f;
#pragma unroll 8
        for (int k = 0; k < IN_F; ++k)
            acc = fmaf(xs[wave][k], w[k * HID_F + lane], acc);
        h[(size_t)row * HID_F + lane] = acc;
    }
}

// One wave per node; lane = feature. acc = self + sum_in(h[src]*w). Optional bias+relu.
template <int RELU>
__global__ __launch_bounds__(256) void csr_agg(const int* __restrict__ rowptr,
                                               const int2* __restrict__ csr,
                                               const float* __restrict__ dinv,
                                               const float* __restrict__ hin,
                                               const float* __restrict__ bias,
                                               float* __restrict__ outv, int n) {
    const int node = blockIdx.x * 4 + (threadIdx.x >> 6);
    if (node >= n) return;
    const int lane = threadIdx.x & 63;
    const int beg = rowptr[node], end = rowptr[node + 1];
    const float dn = dinv[node];
    float acc = hin[(size_t)node * HID_F + lane] * dn * dn;   // self loop
    for (int p = beg; p < end; ++p) {
        int2 ew = csr[p];                       // uniform across wave (broadcast)
        acc = fmaf(hin[(size_t)ew.x * HID_F + lane], __int_as_float(ew.y), acc);
    }
    if (RELU) {
        acc += bias[lane];
        acc = fmaxf(acc, 0.f);
    }
    outv[(size_t)node * HID_F + lane] = acc;
}

// out[n][96] = agg[n][64] @ W2[64][96] + b2
__global__ __launch_bounds__(256) void gemm2(const float* __restrict__ agg,
                                             const float* __restrict__ W2,
                                             const float* __restrict__ b2,
                                             float* __restrict__ out, int n) {
    __shared__ float w[HID_F * OUT_F];  // 24 KiB
    __shared__ float bs[OUT_F];
    for (int i = threadIdx.x; i < HID_F * OUT_F; i += 256) w[i] = W2[i];
    for (int i = threadIdx.x; i < OUT_F; i += 256) bs[i] = b2[i];
    __syncthreads();
    int total = n * OUT_F;
    for (int idx = blockIdx.x * 256 + threadIdx.x; idx < total; idx += gridDim.x * 256) {
        int r = idx / OUT_F, j = idx - r * OUT_F;
        const float* a = agg + (size_t)r * HID_F;
        float acc = bs[j];
#pragma unroll
        for (int k = 0; k < HID_F; ++k)
            acc = fmaf(a[k], w[k * OUT_F + j], acc);
        out[idx] = acc;
    }
}

extern "C" void kernel_launch(void* const* d_in, const int* in_sizes, int n_in,
                              void* d_out, int out_size, void* d_ws, size_t ws_size,
                              hipStream_t stream) {
    const float* x  = (const float*)d_in[0];
    const int*   ei = (const int*)d_in[1];
    const float* W1 = (const float*)d_in[2];
    const float* b1 = (const float*)d_in[3];
    const float* W2 = (const float*)d_in[4];
    const float* b2 = (const float*)d_in[5];
    float* out = (float*)d_out;

    const int n = in_sizes[0] / IN_F;     // 100000
    const int E = in_sizes[1] / 2;        // 1600000
    const int* src = ei;
    const int* dst = ei + E;
    const int NB = (n + 1023) / 1024;     // scan blocks (98)

    char* ws = (char*)d_ws;
    size_t off = 0;
    auto alloc = [&](size_t bytes) { void* p = ws + off; off = (off + bytes + 255) & ~(size_t)255; return p; };
    int*   deg      = (int*)alloc((size_t)n * 4);
    float* dinv     = (float*)alloc((size_t)n * 4);
    int*   pre      = (int*)alloc((size_t)n * 4);
    int*   rowptr   = (int*)alloc((size_t)(n + 1) * 4);
    int*   writepos = (int*)alloc((size_t)n * 4);
    int*   bsum     = (int*)alloc(256 * 4);
    int*   boffs    = (int*)alloc(256 * 4);
    int2*  csr      = (int2*)alloc((size_t)E * 8);
    float* bufA     = (float*)alloc((size_t)n * HID_F * 4);
    float* bufB     = (float*)alloc((size_t)n * HID_F * 4);

    // degree + normalization
    zero_deg <<<512, 256, 0, stream>>>(deg, n);
    count_deg<<<2048, 256, 0, stream>>>(dst, deg, E);
    calc_dinv<<<512, 256, 0, stream>>>(deg, dinv, n);

    // CSR build
    scan_blocks<<<NB, 256, 0, stream>>>(deg, pre, bsum, n);
    scan_bsums <<<1, 256, 0, stream>>>(bsum, boffs, NB);
    add_offsets<<<512, 256, 0, stream>>>(pre, boffs, rowptr, writepos, n, E);
    fill_csr   <<<2048, 256, 0, stream>>>(src, dst, dinv, writepos, csr, E);

    // layer 1
    gemm1      <<<2048, 256, 0, stream>>>(x, W1, bufA, n);
    csr_agg<1> <<<(n + 3) / 4, 256, 0, stream>>>(rowptr, csr, dinv, bufA, b1, bufB, n);

    // layer 2
    csr_agg<0> <<<(n + 3) / 4, 256, 0, stream>>>(rowptr, csr, dinv, bufB, NULL, bufA, n);
    gemm2      <<<2048, 256, 0, stream>>>(bufA, W2, b2, out, n);
}

// Round 3
// 452.279 us; speedup vs baseline: 2.0937x; 1.3734x over previous
//
#include <hip/hip_runtime.h>

// ConformalGCN: 2-layer GCN, N=100000, E=1600000 (+self loops), fp32.
// R2: csr_agg edge loop unrolled x8 with independent gathers (raise MLP;
//     R1 showed latency-bound: VALU 16%, BW 18%, VGPR=8 -> no lookahead).

#define IN_F  128
#define HID_F 64
#define OUT_F 96

__global__ __launch_bounds__(256) void zero_deg(int* __restrict__ deg, int n) {
    for (int i = blockIdx.x * 256 + threadIdx.x; i < n; i += gridDim.x * 256)
        deg[i] = 0;
}

__global__ __launch_bounds__(256) void count_deg(const int* __restrict__ dst,
                                                 int* __restrict__ deg, int E) {
    for (int e = blockIdx.x * 256 + threadIdx.x; e < E; e += gridDim.x * 256)
        atomicAdd(&deg[dst[e]], 1);
}

__global__ __launch_bounds__(256) void calc_dinv(const int* __restrict__ deg,
                                                 float* __restrict__ dinv, int n) {
    for (int i = blockIdx.x * 256 + threadIdx.x; i < n; i += gridDim.x * 256)
        dinv[i] = rsqrtf((float)(deg[i] + 1));   // +1 self loop; always > 0
}

// ---- hierarchical exclusive prefix sum over deg[n] (1024 elems/block) ----
__global__ __launch_bounds__(256) void scan_blocks(const int* __restrict__ deg,
                                                   int* __restrict__ pre,
                                                   int* __restrict__ bsum, int n) {
    __shared__ int lds[256];
    const int t = threadIdx.x;
    const int base = blockIdx.x * 1024 + t * 4;
    int v0 = (base + 0 < n) ? deg[base + 0] : 0;
    int v1 = (base + 1 < n) ? deg[base + 1] : 0;
    int v2 = (base + 2 < n) ? deg[base + 2] : 0;
    int v3 = (base + 3 < n) ? deg[base + 3] : 0;
    int s = v0 + v1 + v2 + v3;
    lds[t] = s;
    __syncthreads();
    for (int off = 1; off < 256; off <<= 1) {
        int add = (t >= off) ? lds[t - off] : 0;
        __syncthreads();
        lds[t] += add;
        __syncthreads();
    }
    int e = lds[t] - s;
    if (base + 0 < n) pre[base + 0] = e;
    e += v0;
    if (base + 1 < n) pre[base + 1] = e;
    e += v1;
    if (base + 2 < n) pre[base + 2] = e;
    e += v2;
    if (base + 3 < n) pre[base + 3] = e;
    if (t == 255) bsum[blockIdx.x] = lds[255];
}

__global__ __launch_bounds__(256) void scan_bsums(const int* __restrict__ bsum,
                                                  int* __restrict__ boffs, int nb) {
    __shared__ int lds[256];
    const int t = threadIdx.x;
    int v = (t < nb) ? bsum[t] : 0;
    lds[t] = v;
    __syncthreads();
    for (int off = 1; off < 256; off <<= 1) {
        int add = (t >= off) ? lds[t - off] : 0;
        __syncthreads();
        lds[t] += add;
        __syncthreads();
    }
    boffs[t] = lds[t] - v;
}

__global__ __launch_bounds__(256) void add_offsets(const int* __restrict__ pre,
                                                   const int* __restrict__ boffs,
                                                   int* __restrict__ rowptr,
                                                   int* __restrict__ writepos,
                                                   int n, int E) {
    for (int i = blockIdx.x * 256 + threadIdx.x; i < n; i += gridDim.x * 256) {
        int r = pre[i] + boffs[i >> 10];
        rowptr[i] = r;
        writepos[i] = r;
        if (i == 0) rowptr[n] = E;
    }
}

// csr[pos] = (src, dinv[src]*dinv[dst] as bits)
__global__ __launch_bounds__(256) void fill_csr(const int* __restrict__ src,
                                                const int* __restrict__ dst,
                                                const float* __restrict__ dinv,
                                                int* __restrict__ writepos,
                                                int2* __restrict__ csr, int E) {
    for (int e = blockIdx.x * 256 + threadIdx.x; e < E; e += gridDim.x * 256) {
        int s = src[e], d = dst[e];
        int pos = atomicAdd(&writepos[d], 1);
        csr[pos] = make_int2(s, __float_as_int(dinv[s] * dinv[d]));
    }
}

// h[n][64] = x[n][128] @ W1[128][64].  One wave per row; lane j owns col j.
__global__ __launch_bounds__(256) void gemm1(const float* __restrict__ x,
                                             const float* __restrict__ W1,
                                             float* __restrict__ h, int n) {
    __shared__ float w[IN_F * HID_F];   // 32 KiB
    __shared__ float xs[4][IN_F];
    for (int i = threadIdx.x; i < IN_F * HID_F; i += 256) w[i] = W1[i];
    __syncthreads();
    const int wave = threadIdx.x >> 6, lane = threadIdx.x & 63;
    for (int row = blockIdx.x * 4 + wave; row < n; row += gridDim.x * 4) {
        float2 v = *(const float2*)(x + (size_t)row * IN_F + lane * 2);
        xs[wave][lane * 2]     = v.x;
        xs[wave][lane * 2 + 1] = v.y;
        float acc = 0.f;
#pragma unroll 8
        for (int k = 0; k < IN_F; ++k)
            acc = fmaf(xs[wave][k], w[k * HID_F + lane], acc);
        h[(size_t)row * HID_F + lane] = acc;
    }
}

// One wave per node; lane = feature. Unrolled x8: 8 edge records + 8
// independent row gathers in flight, 2 accumulators to split the fma chain.
template <int RELU>
__global__ __launch_bounds__(256) void csr_agg(const int* __restrict__ rowptr,
                                               const int2* __restrict__ csr,
                                               const float* __restrict__ dinv,
                                               const float* __restrict__ hin,
                                               const float* __restrict__ bias,
                                               float* __restrict__ outv, int n) {
    const int node = blockIdx.x * 4 + (threadIdx.x >> 6);
    if (node >= n) return;
    const int lane = threadIdx.x & 63;
    const int beg = rowptr[node], end = rowptr[node + 1];
    const float dn = dinv[node];
    float acc0 = hin[(size_t)node * HID_F + lane] * dn * dn;   // self loop
    float acc1 = 0.f;
    int p = beg;
    for (; p + 8 <= end; p += 8) {
        int2 e0 = csr[p + 0], e1 = csr[p + 1], e2 = csr[p + 2], e3 = csr[p + 3];
        int2 e4 = csr[p + 4], e5 = csr[p + 5], e6 = csr[p + 6], e7 = csr[p + 7];
        float v0 = hin[(size_t)e0.x * HID_F + lane];
        float v1 = hin[(size_t)e1.x * HID_F + lane];
        float v2 = hin[(size_t)e2.x * HID_F + lane];
        float v3 = hin[(size_t)e3.x * HID_F + lane];
        float v4 = hin[(size_t)e4.x * HID_F + lane];
        float v5 = hin[(size_t)e5.x * HID_F + lane];
        float v6 = hin[(size_t)e6.x * HID_F + lane];
        float v7 = hin[(size_t)e7.x * HID_F + lane];
        acc0 = fmaf(v0, __int_as_float(e0.y), acc0);
        acc1 = fmaf(v1, __int_as_float(e1.y), acc1);
        acc0 = fmaf(v2, __int_as_float(e2.y), acc0);
        acc1 = fmaf(v3, __int_as_float(e3.y), acc1);
        acc0 = fmaf(v4, __int_as_float(e4.y), acc0);
        acc1 = fmaf(v5, __int_as_float(e5.y), acc1);
        acc0 = fmaf(v6, __int_as_float(e6.y), acc0);
        acc1 = fmaf(v7, __int_as_float(e7.y), acc1);
    }
    if (p + 4 <= end) {
        int2 e0 = csr[p + 0], e1 = csr[p + 1], e2 = csr[p + 2], e3 = csr[p + 3];
        float v0 = hin[(size_t)e0.x * HID_F + lane];
        float v1 = hin[(size_t)e1.x * HID_F + lane];
        float v2 = hin[(size_t)e2.x * HID_F + lane];
        float v3 = hin[(size_t)e3.x * HID_F + lane];
        acc0 = fmaf(v0, __int_as_float(e0.y), acc0);
        acc1 = fmaf(v1, __int_as_float(e1.y), acc1);
        acc0 = fmaf(v2, __int_as_float(e2.y), acc0);
        acc1 = fmaf(v3, __int_as_float(e3.y), acc1);
        p += 4;
    }
    for (; p < end; ++p) {
        int2 ew = csr[p];
        acc0 = fmaf(hin[(size_t)ew.x * HID_F + lane], __int_as_float(ew.y), acc0);
    }
    float acc = acc0 + acc1;
    if (RELU) {
        acc += bias[lane];
        acc = fmaxf(acc, 0.f);
    }
    outv[(size_t)node * HID_F + lane] = acc;
}

// out[n][96] = agg[n][64] @ W2[64][96] + b2
__global__ __launch_bounds__(256) void gemm2(const float* __restrict__ agg,
                                             const float* __restrict__ W2,
                                             const float* __restrict__ b2,
                                             float* __restrict__ out, int n) {
    __shared__ float w[HID_F * OUT_F];  // 24 KiB
    __shared__ float bs[OUT_F];
    for (int i = threadIdx.x; i < HID_F * OUT_F; i += 256) w[i] = W2[i];
    for (int i = threadIdx.x; i < OUT_F; i += 256) bs[i] = b2[i];
    __syncthreads();
    int total = n * OUT_F;
    for (int idx = blockIdx.x * 256 + threadIdx.x; idx < total; idx += gridDim.x * 256) {
        int r = idx / OUT_F, j = idx - r * OUT_F;
        const float* a = agg + (size_t)r * HID_F;
        float acc = bs[j];
#pragma unroll
        for (int k = 0; k < HID_F; ++k)
            acc = fmaf(a[k], w[k * OUT_F + j], acc);
        out[idx] = acc;
    }
}

extern "C" void kernel_launch(void* const* d_in, const int* in_sizes, int n_in,
                              void* d_out, int out_size, void* d_ws, size_t ws_size,
                              hipStream_t stream) {
    const float* x  = (const float*)d_in[0];
    const int*   ei = (const int*)d_in[1];
    const float* W1 = (const float*)d_in[2];
    const float* b1 = (const float*)d_in[3];
    const float* W2 = (const float*)d_in[4];
    const float* b2 = (const float*)d_in[5];
    float* out = (float*)d_out;

    const int n = in_sizes[0] / IN_F;     // 100000
    const int E = in_sizes[1] / 2;        // 1600000
    const int* src = ei;
    const int* dst = ei + E;
    const int NB = (n + 1023) / 1024;     // scan blocks (98)

    char* ws = (char*)d_ws;
    size_t off = 0;
    auto alloc = [&](size_t bytes) { void* p = ws + off; off = (off + bytes + 255) & ~(size_t)255; return p; };
    int*   deg      = (int*)alloc((size_t)n * 4);
    float* dinv     = (float*)alloc((size_t)n * 4);
    int*   pre      = (int*)alloc((size_t)n * 4);
    int*   rowptr   = (int*)alloc((size_t)(n + 1) * 4);
    int*   writepos = (int*)alloc((size_t)n * 4);
    int*   bsum     = (int*)alloc(256 * 4);
    int*   boffs    = (int*)alloc(256 * 4);
    int2*  csr      = (int2*)alloc((size_t)E * 8);
    float* bufA     = (float*)alloc((size_t)n * HID_F * 4);
    float* bufB     = (float*)alloc((size_t)n * HID_F * 4);

    // degree + normalization
    zero_deg <<<512, 256, 0, stream>>>(deg, n);
    count_deg<<<2048, 256, 0, stream>>>(dst, deg, E);
    calc_dinv<<<512, 256, 0, stream>>>(deg, dinv, n);

    // CSR build
    scan_blocks<<<NB, 256, 0, stream>>>(deg, pre, bsum, n);
    scan_bsums <<<1, 256, 0, stream>>>(bsum, boffs, NB);
    add_offsets<<<512, 256, 0, stream>>>(pre, boffs, rowptr, writepos, n, E);
    fill_csr   <<<2048, 256, 0, stream>>>(src, dst, dinv, writepos, csr, E);

    // layer 1
    gemm1      <<<2048, 256, 0, stream>>>(x, W1, bufA, n);
    csr_agg<1> <<<(n + 3) / 4, 256, 0, stream>>>(rowptr, csr, dinv, bufA, b1, bufB, n);

    // layer 2
    csr_agg<0> <<<(n + 3) / 4, 256, 0, stream>>>(rowptr, csr, dinv, bufB, NULL, bufA, n);
    gemm2      <<<2048, 256, 0, stream>>>(bufA, W2, b2, out, n);
}